// Round 14
// baseline (202.696 us; speedup 1.0000x reference)
//
#include <hip/hip_runtime.h>
#include <stdint.h>

#define N_BOX 8400
#define NCLS 80
#define PSTRIDE 85
#define NW 132            // 64-box blocks covering 8400
#define NTILE 8778        // NW*(NW+1)/2 upper-tri tiles
#define ZROWI N_BOX       // mask row 8400 = all zeros (dummy row target)
#define CONF_T 0.01f
#define NMS_T 0.2f

typedef unsigned long long u64;

// ws layout (bytes). diagT/sup1/sup2/sup3 ALIAS det+keys: both dead after
// rank_k; tiles written by mask_k (later in-stream) — lifetimes disjoint
// (same-stream kernels serialize).
#define OFF_DET     0                    // 8400 x 8 f32   = 268800
#define OFF_DIAGT   0                    // 132*64 u64     = 67584  (alias)
#define OFF_SUP1    67584                // 132*64 u64     = 67584  (alias)
#define OFF_SUP2    135168               // 132*64 u64     = 67584  (alias)
#define OFF_SUP3    202752               // 132*64 u64     = 67584  (alias, tail overlaps keys head — keys dead then)
#define OFF_KEYS    268800               // 8400 u64       = 67200
#define OFF_DETS    336000               // 8400 x 8 f32   = 268800
#define OFF_BOXESS  604800               // 8400 float4    = 134400
#define OFF_MASK    739200               // 8401 x 132 u64 = 8871456 (row 8400 = zeros)
#define OFF_VCNT    9611712              // 1 int

__device__ __forceinline__ unsigned fmap_desc(float f) {
    unsigned u = __float_as_uint(f);
    unsigned m = (u & 0x80000000u) ? ~u : (u | 0x80000000u); // monotone ascending
    return ~m;                                               // descending
}

__device__ __forceinline__ u64 readlane64(u64 v, int lane) {
    unsigned lo = (unsigned)__builtin_amdgcn_readlane((int)(unsigned)v, lane);
    unsigned hi = (unsigned)__builtin_amdgcn_readlane((int)(unsigned)(v >> 32), lane);
    return ((u64)hi << 32) | lo;
}

__device__ __forceinline__ u64 shfl_xor64(u64 v, int m) {
    int lo = __shfl_xor((int)(unsigned)v, m);
    int hi = __shfl_xor((int)(unsigned)(v >> 32), m);
    return ((u64)(unsigned)hi << 32) | (unsigned)lo;
}

// 64x64 bit-matrix transpose across lanes. Verified R8-R13 (absmax 0).
__device__ __forceinline__ u64 bittranspose64(u64 x, int lane) {
    const u64 P0 = 0x5555555555555555ull, P1 = 0x3333333333333333ull,
              P2 = 0x0F0F0F0F0F0F0F0Full, P3 = 0x00FF00FF00FF00FFull,
              P4 = 0x0000FFFF0000FFFFull, P5 = 0x00000000FFFFFFFFull;
#define TSTEP(s, p) do {                                                 \
        u64 y = shfl_xor64(x, s);                                        \
        x = (lane & (s)) ? ((x & ~(p)) | ((y & ~(p)) >> (s)))            \
                         : ((x & (p))  | ((y & (p))  << (s)));           \
    } while (0)
    TSTEP(1, P0); TSTEP(2, P1); TSTEP(4, P2);
    TSTEP(8, P3); TSTEP(16, P4); TSTEP(32, P5);
#undef TSTEP
    return x;
}

__device__ __forceinline__ u64 wmask(int w, int V) {
    int nb = V - (w << 6);
    if (nb <= 0) return 0ull;
    if (nb >= 64) return ~0ull;
    return (1ull << nb) - 1ull;
}

// Raw barrier: LDS drained, vmcnt pipeline PRESERVED (no __syncthreads drain).
__device__ __forceinline__ void step_barrier() {
    asm volatile("s_waitcnt lgkmcnt(0)" ::: "memory");
    __builtin_amdgcn_s_barrier();
    asm volatile("" ::: "memory");
}

// ---- kernel A: per-row preprocess, 4 lanes per row; zeroes mask row 8400 ----
__global__ __launch_bounds__(256) void prep_k(const float* __restrict__ pred,
                                              float* __restrict__ det,
                                              u64* __restrict__ keys,
                                              u64* __restrict__ mask) {
    if (blockIdx.x == 0 && threadIdx.x < NW)
        mask[(size_t)ZROWI * NW + threadIdx.x] = 0ull;
    int gt = blockIdx.x * 256 + threadIdx.x;
    int i = gt >> 2, q = gt & 3;
    if (i >= N_BOX) return;
    const float* p = pred + (size_t)i * PSTRIDE;
    int cbase = q * 20;
    float best = p[5 + cbase];
    int arg = cbase;
    for (int c = 1; c < 20; ++c) {
        float v = p[5 + cbase + c];
        if (v > best) { best = v; arg = cbase + c; }   // strict > : first max in segment
    }
    // quad-combine: larger value wins; tie -> smaller class index (numpy first-max)
    for (int d = 1; d < 4; d <<= 1) {
        float ob = __shfl_xor(best, d);
        int   oa = __shfl_xor(arg, d);
        if (ob > best || (ob == best && oa < arg)) { best = ob; arg = oa; }
    }
    if (q == 0) {
        float cx = p[0], cy = p[1], w = p[2], h = p[3], obj = p[4];
        float hw = __fmul_rn(w, 0.5f), hh = __fmul_rn(h, 0.5f);
        float x1 = __fsub_rn(cx, hw), y1 = __fsub_rn(cy, hh);
        float x2 = __fadd_rn(cx, hw), y2 = __fadd_rn(cy, hh);
        bool valid = (obj >= CONF_T);
        float score = valid ? obj : -1.0f;
        keys[i] = ((u64)fmap_desc(score) << 32) | (unsigned)i;  // asc => score desc, idx asc
        float4* dr = (float4*)(det + (size_t)i * 8);
        dr[0] = make_float4(x1, y1, x2, y2);
        dr[1] = make_float4(obj, best, (float)arg, 0.0f);
    }
}

// ---- kernel B: rank + scatter. u64 keys (index embedded), 8 j-slices. ----
__global__ __launch_bounds__(256) void rank_k(const u64* __restrict__ keys,
                                              const float* __restrict__ det,
                                              float4* __restrict__ det_s,
                                              float4* __restrict__ boxes_s,
                                              int* __restrict__ vcount) {
    int t = threadIdx.x;
    int i = blockIdx.x * 32 + (t & 31);
    int s = t >> 5;                    // slice 0..7, 1050 keys each
    u64 my = (i < N_BOX) ? keys[i] : ~0ull;
    int cnt = 0, cv = 0;
    int j0 = s * 1050, j1 = j0 + 1050;
    for (int j = j0; j < j1; j += 2) {
        ulonglong2 kk = *(const ulonglong2*)(keys + j);
        cnt += (kk.x < my) + (kk.y < my);
        cv  += ((long long)kk.x >= 0) + ((long long)kk.y >= 0);
    }
    __shared__ int sc[256], sv[256];
    sc[t] = cnt; sv[t] = cv;
    __syncthreads();
    if (t < 32) {
        int r = sc[t] + sc[t + 32] + sc[t + 64] + sc[t + 96]
              + sc[t + 128] + sc[t + 160] + sc[t + 192] + sc[t + 224];
        if (i < N_BOX) {
            const float4* dr = (const float4*)(det + (size_t)i * 8);
            float4 b0 = dr[0], b1 = dr[1];
            det_s[(size_t)r * 2]     = b0;
            det_s[(size_t)r * 2 + 1] = b1;
            boxes_s[r] = b0;
        }
        if (blockIdx.x == 0 && t == 0) {
            *vcount = sv[0] + sv[32] + sv[64] + sv[96]
                    + sv[128] + sv[160] + sv[192] + sv[224];
        }
    }
}

// ---- kernel C: suppression bitmask (upper tri, row-major) + transposed
// near-diagonal tiles diagT/sup1/sup2/sup3 (distance 0..3). 4 tiles/block. ----
__global__ __launch_bounds__(256) void mask_k(const float4* __restrict__ boxes_s,
                                              u64* __restrict__ mask,
                                              u64* __restrict__ diagT,
                                              u64* __restrict__ sup1,
                                              u64* __restrict__ sup2,
                                              u64* __restrict__ sup3) {
    int sub = threadIdx.x >> 6, lane = threadIdx.x & 63;
    int tt = blockIdx.x * 4 + sub;
    bool tv = (tt < NTILE);
    __shared__ float4 cB[4][64];
    __shared__ float  cA[4][64];
    int rb = 0, cb = 0;
    if (tv) {
        rb = (int)((2.0f * NW + 1.0f
                    - sqrtf((2.0f * NW + 1.0f) * (2.0f * NW + 1.0f) - 8.0f * (float)tt)) * 0.5f);
        while (rb > 0 && rb * NW - rb * (rb - 1) / 2 > tt) rb--;
        while ((rb + 1) * NW - (rb + 1) * rb / 2 <= tt) rb++;
        cb = rb + (tt - (rb * NW - rb * (rb - 1) / 2));
        int c0 = cb * 64 + lane;
        float4 b = (c0 < N_BOX) ? boxes_s[c0] : make_float4(0.f, 0.f, 0.f, 0.f);
        cB[sub][lane] = b;
        cA[sub][lane] = __fmul_rn(__fsub_rn(b.z, b.x), __fsub_rn(b.w, b.y));
    }
    __syncthreads();
    if (!tv) return;
    int r = rb * 64 + lane;
    bool inb = (r < N_BOX);
    float4 rx = boxes_s[inb ? r : (N_BOX - 1)];
    float ra = __fmul_rn(__fsub_rn(rx.z, rx.x), __fsub_rn(rx.w, rx.y));
    u64 bits = 0ull;
    int cbase = cb * 64;
    for (int j = 0; j < 64; ++j) {
        int c = cbase + j;
        if (c >= N_BOX || c <= r) continue;    // rows >= N_BOX yield bits==0
        float4 cx4 = cB[sub][j];
        float ltx = fmaxf(rx.x, cx4.x), lty = fmaxf(rx.y, cx4.y);
        float rbx = fminf(rx.z, cx4.z), rby = fminf(rx.w, cx4.w);
        float wx = fmaxf(__fsub_rn(rbx, ltx), 0.0f);
        float wy = fmaxf(__fsub_rn(rby, lty), 0.0f);
        float inter = __fmul_rn(wx, wy);
        float denom = __fadd_rn(__fsub_rn(__fadd_rn(ra, cA[sub][j]), inter), 1e-9f);
        float iou = __fdiv_rn(inter, denom);
        if (iou > NMS_T) bits |= (1ull << j);
    }
    if (inb) mask[(size_t)r * NW + cb] = bits;
    int d = cb - rb;
    if (d <= 3) {
        u64 tb = bittranspose64(bits, lane);
        size_t idx = (size_t)cb * 64 + lane;
        if (d == 0)      diagT[idx] = tb;
        else if (d == 1) sup1[idx]  = tb;
        else if (d == 2) sup2[idx]  = tb;
        else             sup3[idx]  = tb;
    }
}

// ---- kernel D: 3-wave producer/consumer greedy scan + fused write-out ----
// wave 0 (resolver), phase k: cur = remvP1[k]|remvP2[k] | ballot patches
//   (sup1..3 x A1..3); resolve leaders via diagT ballots; Lbuf[k] (= keep mask).
// waves 1,2 (row-OR, split by leader-word half), phase j: consume own 4-slot
//   set issued at phase j-2 (rows of block j-3); publish own remvP[j+1]
//   (covers rows <= j-3 — meets wave0's k-4 deadline; sup1..3 patch 1..3);
//   read Lbuf[j-1], issue own <=4 slot loads (dummy -> zero row); extras
//   (>4 in own half) drain immediately in 8-row batches.
// Raw s_barrier per phase preserves each wave's vmcnt pipeline.
// Tail: masked 7-col write-out using Lbuf directly (out_k fused away).
__global__ __launch_bounds__(192, 1) void scan_k(const u64* __restrict__ mask,
                                                 const u64* __restrict__ diagT,
                                                 const u64* __restrict__ sup1,
                                                 const u64* __restrict__ sup2,
                                                 const u64* __restrict__ sup3,
                                                 const int* __restrict__ vcount,
                                                 const float* __restrict__ det_s,
                                                 float* __restrict__ out) {
    __shared__ u64 remvP1[NW + 2];
    __shared__ u64 remvP2[NW + 2];
    __shared__ u64 Lbuf[NW];
    int tid = threadIdx.x, lane = tid & 63, wv = tid >> 6;
    int V = *vcount;
    for (int i = tid; i < NW + 2; i += 192) { remvP1[i] = 0ull; remvP2[i] = 0ull; }
    __syncthreads();

    if (wv == 0) {
        // ---------------- wave 0: resolver ----------------
        u64 A1 = 0ull, A2 = 0ull, A3 = 0ull;
        u64 d0P, s1P, s2P, s3P, d0Q, s1Q, s2Q, s3Q;
#define TL(S, kk) do {                                                   \
        int t_ = (kk) < NW ? (kk) : (NW - 1);                            \
        size_t ix_ = (size_t)t_ * 64 + lane;                             \
        d0##S = diagT[ix_]; s1##S = sup1[ix_];                           \
        s2##S = sup2[ix_];  s3##S = sup3[ix_];                           \
    } while (0)
#define STEP0(kk, S) do {                                                \
        int k_ = (kk);                                                   \
        u64 cur_ = remvP1[k_] | remvP2[k_];                              \
        cur_ |= __ballot((s1##S & A1) != 0ull);                          \
        cur_ |= __ballot((s2##S & A2) != 0ull);                          \
        cur_ |= __ballot((s3##S & A3) != 0ull);                          \
        u64 m_ = wmask(k_, V);                                           \
        u64 ns_ = (~cur_) & m_;                                          \
        u64 L_ = 0ull;                                                   \
        while (ns_) {                                                    \
            int b_ = __builtin_ctzll(ns_);                               \
            L_ |= 1ull << b_;                                            \
            u64 sup_ = __ballot((int)((d0##S >> b_) & 1ull));            \
            ns_ &= ~sup_;                                                \
            ns_ &= ~(1ull << b_);                                        \
        }                                                                \
        if (lane == 0) Lbuf[k_] = L_;                                    \
        A3 = A2; A2 = A1; A1 = L_;                                       \
        TL(S, k_ + 2);                                                   \
        step_barrier();                                                  \
    } while (0)
        TL(P, 0);
        TL(Q, 1);
        for (int c = 0; c < NW; c += 2) {
            STEP0(c + 0, P);
            STEP0(c + 1, Q);
        }
#undef STEP0
#undef TL
    } else {
        // ---------------- waves 1,2: row-OR, split by half-word ----------------
        int half = wv - 1;                     // 0: leader bits 0..31, 1: 32..63
        u64* myP = half ? remvP2 : remvP1;
        int tw = (lane < 4) ? (128 + lane) : 131;
        u64 Ra = 0ull, Rb = 0ull, Rc = 0ull;   // this wave's partial remv
        u64 Pa0=0,Pa1=0,Pa2=0,Pa3=0, Pb0=0,Pb1=0,Pb2=0,Pb3=0, Pc0=0,Pc1=0,Pc2=0,Pc3=0;
        u64 Qa0=0,Qa1=0,Qa2=0,Qa3=0, Qb0=0,Qb1=0,Qb2=0,Qb3=0, Qc0=0,Qc1=0,Qc2=0,Qc3=0;

#define CONS(S) do {                                                     \
        Ra |= (S##a0 | S##a1) | (S##a2 | S##a3);                         \
        Rb |= (S##b0 | S##b1) | (S##b2 | S##b3);                         \
        Rc |= (S##c0 | S##c1) | (S##c2 | S##c3);                         \
    } while (0)

#define LROW(S, i) do {                                                  \
        size_t ri_ = rem_ ? (size_t)(rbase_ + __builtin_ctz(rem_))       \
                          : (size_t)ZROWI;                               \
        rem_ &= rem_ - 1u;                                               \
        const u64* rp_ = mask + ri_ * NW;                                \
        ulonglong2 v_ = *(const ulonglong2*)(rp_ + 2 * lane);            \
        S##a##i = v_.x; S##b##i = v_.y; S##c##i = rp_[tw];               \
    } while (0)

#define STEP1(jj, S) do {                                                \
        int j_ = (jj);                                                   \
        CONS(S);                               /* rows of block j-3 */   \
        int w_ = j_ + 1;                                                 \
        u64 rw_ = (w_ < 128) ? ((w_ & 1) ? Rb : Ra) : Rc;                \
        int sl_ = (w_ < 128) ? (w_ >> 1) : (w_ - 128);                   \
        u64 pv_ = readlane64(rw_, sl_);                                  \
        if (lane == 0) myP[w_] = pv_;                                    \
        u64 Lfull_ = (j_ >= 1) ? Lbuf[j_ - 1] : 0ull;                    \
        unsigned rem_ = half ? (unsigned)(Lfull_ >> 32)                  \
                             : (unsigned)Lfull_;                         \
        int rbase_ = ((j_ - 1) << 6) + 32 * half;                        \
        LROW(S, 0); LROW(S, 1); LROW(S, 2); LROW(S, 3);                  \
        while (rem_) {                          /* extras: 8/batch */    \
            u64 xa_ = 0, xb_ = 0, xc_ = 0;                               \
            for (int q_ = 0; q_ < 8; ++q_) {                             \
                size_t ri_ = rem_ ? (size_t)(rbase_ + __builtin_ctz(rem_)) \
                                  : (size_t)ZROWI;                       \
                rem_ &= rem_ - 1u;                                       \
                const u64* rp_ = mask + ri_ * NW;                        \
                ulonglong2 v_ = *(const ulonglong2*)(rp_ + 2 * lane);    \
                xa_ |= v_.x; xb_ |= v_.y; xc_ |= rp_[tw];                \
            }                                                            \
            Ra |= xa_; Rb |= xb_; Rc |= xc_;                             \
        }                                                                \
        step_barrier();                                                  \
    } while (0)

        for (int c = 0; c < NW; c += 2) {
            STEP1(c + 0, P);
            STEP1(c + 1, Q);
        }
#undef STEP1
#undef LROW
#undef CONS
    }

    // ---- fused masked write-out (7 cols); Lbuf = keep mask ----
    __syncthreads();
    for (int e = tid; e < N_BOX * 7; e += 192) {
        int r = e / 7, c = e - r * 7;
        bool k = (Lbuf[r >> 6] >> (r & 63)) & 1ull;
        out[e] = k ? det_s[(size_t)r * 8 + c] : 0.0f;
    }
}

extern "C" void kernel_launch(void* const* d_in, const int* in_sizes, int n_in,
                              void* d_out, int out_size, void* d_ws, size_t ws_size,
                              hipStream_t stream) {
    const float* pred = (const float*)d_in[0];
    char* ws = (char*)d_ws;
    float*    det     = (float*)   (ws + OFF_DET);
    u64*      diagT   = (u64*)     (ws + OFF_DIAGT);
    u64*      sup1    = (u64*)     (ws + OFF_SUP1);
    u64*      sup2    = (u64*)     (ws + OFF_SUP2);
    u64*      sup3    = (u64*)     (ws + OFF_SUP3);
    u64*      keys    = (u64*)     (ws + OFF_KEYS);
    float*    det_s   = (float*)   (ws + OFF_DETS);
    float4*   boxes_s = (float4*)  (ws + OFF_BOXESS);
    u64*      mask    = (u64*)     (ws + OFF_MASK);
    int*      vcount  = (int*)     (ws + OFF_VCNT);

    prep_k<<<132, 256, 0, stream>>>(pred, det, keys, mask);
    rank_k<<<264, 256, 0, stream>>>(keys, det, (float4*)det_s, boxes_s, vcount);
    mask_k<<<(NTILE + 3) / 4, 256, 0, stream>>>(boxes_s, mask, diagT, sup1, sup2, sup3);
    scan_k<<<1, 192, 0, stream>>>(mask, diagT, sup1, sup2, sup3, vcount,
                                  det_s, (float*)d_out);
}

// Round 15
// 143.188 us; speedup vs baseline: 1.4156x; 1.4156x over previous
//
#include <hip/hip_runtime.h>
#include <stdint.h>

#define N_BOX 8400
#define NCLS 80
#define PSTRIDE 85
#define NW 132            // 64-box blocks covering 8400
#define NTILE 8778        // NW*(NW+1)/2 upper-tri tiles
#define ZROWI N_BOX       // mask row 8400 = all zeros (dummy row target)
#define CONF_T 0.01f
#define NMS_T 0.2f

typedef unsigned long long u64;

// ws layout (bytes). diagT/sup1/sup2/sup3 ALIAS det+keys: both dead after
// rank_k; tiles written by mask_k (later in-stream) — lifetimes disjoint
// (same-stream kernels serialize).
#define OFF_DET     0                    // 8400 x 8 f32   = 268800
#define OFF_DIAGT   0                    // 132*64 u64     = 67584  (alias)
#define OFF_SUP1    67584                // 132*64 u64     = 67584  (alias)
#define OFF_SUP2    135168               // 132*64 u64     = 67584  (alias)
#define OFF_SUP3    202752               // 132*64 u64     = 67584  (alias, tail overlaps keys head — keys dead then)
#define OFF_KEYS    268800               // 8400 u64       = 67200
#define OFF_DETS    336000               // 8400 x 8 f32   = 268800
#define OFF_BOXESS  604800               // 8400 float4    = 134400
#define OFF_MASK    739200               // 8401 x 132 u64 = 8871456 (row 8400 = zeros)
#define OFF_VCNT    9611712              // 1 int

__device__ __forceinline__ unsigned fmap_desc(float f) {
    unsigned u = __float_as_uint(f);
    unsigned m = (u & 0x80000000u) ? ~u : (u | 0x80000000u); // monotone ascending
    return ~m;                                               // descending
}

__device__ __forceinline__ u64 readlane64(u64 v, int lane) {
    unsigned lo = (unsigned)__builtin_amdgcn_readlane((int)(unsigned)v, lane);
    unsigned hi = (unsigned)__builtin_amdgcn_readlane((int)(unsigned)(v >> 32), lane);
    return ((u64)hi << 32) | lo;
}

__device__ __forceinline__ u64 shfl_xor64(u64 v, int m) {
    int lo = __shfl_xor((int)(unsigned)v, m);
    int hi = __shfl_xor((int)(unsigned)(v >> 32), m);
    return ((u64)(unsigned)hi << 32) | (unsigned)lo;
}

// 64x64 bit-matrix transpose across lanes. Verified R8-R14 (absmax 0).
__device__ __forceinline__ u64 bittranspose64(u64 x, int lane) {
    const u64 P0 = 0x5555555555555555ull, P1 = 0x3333333333333333ull,
              P2 = 0x0F0F0F0F0F0F0F0Full, P3 = 0x00FF00FF00FF00FFull,
              P4 = 0x0000FFFF0000FFFFull, P5 = 0x00000000FFFFFFFFull;
#define TSTEP(s, p) do {                                                 \
        u64 y = shfl_xor64(x, s);                                        \
        x = (lane & (s)) ? ((x & ~(p)) | ((y & ~(p)) >> (s)))            \
                         : ((x & (p))  | ((y & (p))  << (s)));           \
    } while (0)
    TSTEP(1, P0); TSTEP(2, P1); TSTEP(4, P2);
    TSTEP(8, P3); TSTEP(16, P4); TSTEP(32, P5);
#undef TSTEP
    return x;
}

__device__ __forceinline__ u64 wmask(int w, int V) {
    int nb = V - (w << 6);
    if (nb <= 0) return 0ull;
    if (nb >= 64) return ~0ull;
    return (1ull << nb) - 1ull;
}

// Raw barrier: LDS drained, vmcnt pipeline PRESERVED (no __syncthreads drain).
__device__ __forceinline__ void step_barrier() {
    asm volatile("s_waitcnt lgkmcnt(0)" ::: "memory");
    __builtin_amdgcn_s_barrier();
    asm volatile("" ::: "memory");
}

// ---- kernel A: per-row preprocess, 4 lanes per row; zeroes mask row 8400 ----
__global__ __launch_bounds__(256) void prep_k(const float* __restrict__ pred,
                                              float* __restrict__ det,
                                              u64* __restrict__ keys,
                                              u64* __restrict__ mask) {
    if (blockIdx.x == 0 && threadIdx.x < NW)
        mask[(size_t)ZROWI * NW + threadIdx.x] = 0ull;
    int gt = blockIdx.x * 256 + threadIdx.x;
    int i = gt >> 2, q = gt & 3;
    if (i >= N_BOX) return;
    const float* p = pred + (size_t)i * PSTRIDE;
    int cbase = q * 20;
    float best = p[5 + cbase];
    int arg = cbase;
    for (int c = 1; c < 20; ++c) {
        float v = p[5 + cbase + c];
        if (v > best) { best = v; arg = cbase + c; }   // strict > : first max in segment
    }
    // quad-combine: larger value wins; tie -> smaller class index (numpy first-max)
    for (int d = 1; d < 4; d <<= 1) {
        float ob = __shfl_xor(best, d);
        int   oa = __shfl_xor(arg, d);
        if (ob > best || (ob == best && oa < arg)) { best = ob; arg = oa; }
    }
    if (q == 0) {
        float cx = p[0], cy = p[1], w = p[2], h = p[3], obj = p[4];
        float hw = __fmul_rn(w, 0.5f), hh = __fmul_rn(h, 0.5f);
        float x1 = __fsub_rn(cx, hw), y1 = __fsub_rn(cy, hh);
        float x2 = __fadd_rn(cx, hw), y2 = __fadd_rn(cy, hh);
        bool valid = (obj >= CONF_T);
        float score = valid ? obj : -1.0f;
        keys[i] = ((u64)fmap_desc(score) << 32) | (unsigned)i;  // asc => score desc, idx asc
        float4* dr = (float4*)(det + (size_t)i * 8);
        dr[0] = make_float4(x1, y1, x2, y2);
        dr[1] = make_float4(obj, best, (float)arg, 0.0f);
    }
}

// ---- kernel B: rank + scatter. u64 keys (index embedded), 8 j-slices. ----
__global__ __launch_bounds__(256) void rank_k(const u64* __restrict__ keys,
                                              const float* __restrict__ det,
                                              float4* __restrict__ det_s,
                                              float4* __restrict__ boxes_s,
                                              int* __restrict__ vcount) {
    int t = threadIdx.x;
    int i = blockIdx.x * 32 + (t & 31);
    int s = t >> 5;                    // slice 0..7, 1050 keys each
    u64 my = (i < N_BOX) ? keys[i] : ~0ull;
    int cnt = 0, cv = 0;
    int j0 = s * 1050, j1 = j0 + 1050;
    for (int j = j0; j < j1; j += 2) {
        ulonglong2 kk = *(const ulonglong2*)(keys + j);
        cnt += (kk.x < my) + (kk.y < my);
        cv  += ((long long)kk.x >= 0) + ((long long)kk.y >= 0);
    }
    __shared__ int sc[256], sv[256];
    sc[t] = cnt; sv[t] = cv;
    __syncthreads();
    if (t < 32) {
        int r = sc[t] + sc[t + 32] + sc[t + 64] + sc[t + 96]
              + sc[t + 128] + sc[t + 160] + sc[t + 192] + sc[t + 224];
        if (i < N_BOX) {
            const float4* dr = (const float4*)(det + (size_t)i * 8);
            float4 b0 = dr[0], b1 = dr[1];
            det_s[(size_t)r * 2]     = b0;
            det_s[(size_t)r * 2 + 1] = b1;
            boxes_s[r] = b0;
        }
        if (blockIdx.x == 0 && t == 0) {
            *vcount = sv[0] + sv[32] + sv[64] + sv[96]
                    + sv[128] + sv[160] + sv[192] + sv[224];
        }
    }
}

// ---- kernel C: suppression bitmask (upper tri, row-major) + transposed
// near-diagonal tiles diagT/sup1/sup2/sup3 (distance 0..3). 4 tiles/block. ----
__global__ __launch_bounds__(256) void mask_k(const float4* __restrict__ boxes_s,
                                              u64* __restrict__ mask,
                                              u64* __restrict__ diagT,
                                              u64* __restrict__ sup1,
                                              u64* __restrict__ sup2,
                                              u64* __restrict__ sup3) {
    int sub = threadIdx.x >> 6, lane = threadIdx.x & 63;
    int tt = blockIdx.x * 4 + sub;
    bool tv = (tt < NTILE);
    __shared__ float4 cB[4][64];
    __shared__ float  cA[4][64];
    int rb = 0, cb = 0;
    if (tv) {
        rb = (int)((2.0f * NW + 1.0f
                    - sqrtf((2.0f * NW + 1.0f) * (2.0f * NW + 1.0f) - 8.0f * (float)tt)) * 0.5f);
        while (rb > 0 && rb * NW - rb * (rb - 1) / 2 > tt) rb--;
        while ((rb + 1) * NW - (rb + 1) * rb / 2 <= tt) rb++;
        cb = rb + (tt - (rb * NW - rb * (rb - 1) / 2));
        int c0 = cb * 64 + lane;
        float4 b = (c0 < N_BOX) ? boxes_s[c0] : make_float4(0.f, 0.f, 0.f, 0.f);
        cB[sub][lane] = b;
        cA[sub][lane] = __fmul_rn(__fsub_rn(b.z, b.x), __fsub_rn(b.w, b.y));
    }
    __syncthreads();
    if (!tv) return;
    int r = rb * 64 + lane;
    bool inb = (r < N_BOX);
    float4 rx = boxes_s[inb ? r : (N_BOX - 1)];
    float ra = __fmul_rn(__fsub_rn(rx.z, rx.x), __fsub_rn(rx.w, rx.y));
    u64 bits = 0ull;
    int cbase = cb * 64;
    for (int j = 0; j < 64; ++j) {
        int c = cbase + j;
        if (c >= N_BOX || c <= r) continue;    // rows >= N_BOX yield bits==0
        float4 cx4 = cB[sub][j];
        float ltx = fmaxf(rx.x, cx4.x), lty = fmaxf(rx.y, cx4.y);
        float rbx = fminf(rx.z, cx4.z), rby = fminf(rx.w, cx4.w);
        float wx = fmaxf(__fsub_rn(rbx, ltx), 0.0f);
        float wy = fmaxf(__fsub_rn(rby, lty), 0.0f);
        float inter = __fmul_rn(wx, wy);
        float denom = __fadd_rn(__fsub_rn(__fadd_rn(ra, cA[sub][j]), inter), 1e-9f);
        float iou = __fdiv_rn(inter, denom);
        if (iou > NMS_T) bits |= (1ull << j);
    }
    if (inb) mask[(size_t)r * NW + cb] = bits;
    int d = cb - rb;
    if (d <= 3) {
        u64 tb = bittranspose64(bits, lane);
        size_t idx = (size_t)cb * 64 + lane;
        if (d == 0)      diagT[idx] = tb;
        else if (d == 1) sup1[idx]  = tb;
        else if (d == 2) sup2[idx]  = tb;
        else             sup3[idx]  = tb;
    }
}

// ---- kernel D: 4-wave scan (3 working + 1 L2-warm) + parallel fused write ----
// wave 0 (resolver), phase k: cur = remvP1[k]|remvP2[k] | ballot patches
//   (sup1..3 x A1..3); resolve leaders via diagT ballots; Lbuf[k] (= keep mask).
// waves 1,2 (row-OR, split by leader-word half), phase j: consume own 4-slot
//   set issued at phase j-2 (rows of block j-3); publish own remvP[j+1];
//   read Lbuf[j-1], issue own <=4 slot loads; extras drain in 8-row batches.
// wave 3: L2-warms det_s (2 float4/lane/phase = 268KB over 132 phases) so the
//   write-out tail hits L2, while matching the barrier count.
// Tail: per-ROW write-out, 256 threads: 2 coalesced float4 loads + 7 scalar
//   stores per row, ~33 independent rows/thread -> latency hidden by ILP.
__global__ __launch_bounds__(256, 1) void scan_k(const u64* __restrict__ mask,
                                                 const u64* __restrict__ diagT,
                                                 const u64* __restrict__ sup1,
                                                 const u64* __restrict__ sup2,
                                                 const u64* __restrict__ sup3,
                                                 const int* __restrict__ vcount,
                                                 const float* __restrict__ det_s,
                                                 float* __restrict__ out) {
    __shared__ u64 remvP1[NW + 2];
    __shared__ u64 remvP2[NW + 2];
    __shared__ u64 Lbuf[NW];
    int tid = threadIdx.x, lane = tid & 63, wv = tid >> 6;
    int V = *vcount;
    for (int i = tid; i < NW + 2; i += 256) { remvP1[i] = 0ull; remvP2[i] = 0ull; }
    __syncthreads();

    if (wv == 0) {
        // ---------------- wave 0: resolver ----------------
        u64 A1 = 0ull, A2 = 0ull, A3 = 0ull;
        u64 d0P, s1P, s2P, s3P, d0Q, s1Q, s2Q, s3Q;
#define TL(S, kk) do {                                                   \
        int t_ = (kk) < NW ? (kk) : (NW - 1);                            \
        size_t ix_ = (size_t)t_ * 64 + lane;                             \
        d0##S = diagT[ix_]; s1##S = sup1[ix_];                           \
        s2##S = sup2[ix_];  s3##S = sup3[ix_];                           \
    } while (0)
#define STEP0(kk, S) do {                                                \
        int k_ = (kk);                                                   \
        u64 cur_ = remvP1[k_] | remvP2[k_];                              \
        cur_ |= __ballot((s1##S & A1) != 0ull);                          \
        cur_ |= __ballot((s2##S & A2) != 0ull);                          \
        cur_ |= __ballot((s3##S & A3) != 0ull);                          \
        u64 m_ = wmask(k_, V);                                           \
        u64 ns_ = (~cur_) & m_;                                          \
        u64 L_ = 0ull;                                                   \
        while (ns_) {                                                    \
            int b_ = __builtin_ctzll(ns_);                               \
            L_ |= 1ull << b_;                                            \
            u64 sup_ = __ballot((int)((d0##S >> b_) & 1ull));            \
            ns_ &= ~sup_;                                                \
            ns_ &= ~(1ull << b_);                                        \
        }                                                                \
        if (lane == 0) Lbuf[k_] = L_;                                    \
        A3 = A2; A2 = A1; A1 = L_;                                       \
        TL(S, k_ + 2);                                                   \
        step_barrier();                                                  \
    } while (0)
        TL(P, 0);
        TL(Q, 1);
        for (int c = 0; c < NW; c += 2) {
            STEP0(c + 0, P);
            STEP0(c + 1, Q);
        }
#undef STEP0
#undef TL
    } else if (wv <= 2) {
        // ---------------- waves 1,2: row-OR, split by half-word ----------------
        int half = wv - 1;                     // 0: leader bits 0..31, 1: 32..63
        u64* myP = half ? remvP2 : remvP1;
        int tw = (lane < 4) ? (128 + lane) : 131;
        u64 Ra = 0ull, Rb = 0ull, Rc = 0ull;   // this wave's partial remv
        u64 Pa0=0,Pa1=0,Pa2=0,Pa3=0, Pb0=0,Pb1=0,Pb2=0,Pb3=0, Pc0=0,Pc1=0,Pc2=0,Pc3=0;
        u64 Qa0=0,Qa1=0,Qa2=0,Qa3=0, Qb0=0,Qb1=0,Qb2=0,Qb3=0, Qc0=0,Qc1=0,Qc2=0,Qc3=0;

#define CONS(S) do {                                                     \
        Ra |= (S##a0 | S##a1) | (S##a2 | S##a3);                         \
        Rb |= (S##b0 | S##b1) | (S##b2 | S##b3);                         \
        Rc |= (S##c0 | S##c1) | (S##c2 | S##c3);                         \
    } while (0)

#define LROW(S, i) do {                                                  \
        size_t ri_ = rem_ ? (size_t)(rbase_ + __builtin_ctz(rem_))       \
                          : (size_t)ZROWI;                               \
        rem_ &= rem_ - 1u;                                               \
        const u64* rp_ = mask + ri_ * NW;                                \
        ulonglong2 v_ = *(const ulonglong2*)(rp_ + 2 * lane);            \
        S##a##i = v_.x; S##b##i = v_.y; S##c##i = rp_[tw];               \
    } while (0)

#define STEP1(jj, S) do {                                                \
        int j_ = (jj);                                                   \
        CONS(S);                               /* rows of block j-3 */   \
        int w_ = j_ + 1;                                                 \
        u64 rw_ = (w_ < 128) ? ((w_ & 1) ? Rb : Ra) : Rc;                \
        int sl_ = (w_ < 128) ? (w_ >> 1) : (w_ - 128);                   \
        u64 pv_ = readlane64(rw_, sl_);                                  \
        if (lane == 0) myP[w_] = pv_;                                    \
        u64 Lfull_ = (j_ >= 1) ? Lbuf[j_ - 1] : 0ull;                    \
        unsigned rem_ = half ? (unsigned)(Lfull_ >> 32)                  \
                             : (unsigned)Lfull_;                         \
        int rbase_ = ((j_ - 1) << 6) + 32 * half;                        \
        LROW(S, 0); LROW(S, 1); LROW(S, 2); LROW(S, 3);                  \
        while (rem_) {                          /* extras: 8/batch */    \
            u64 xa_ = 0, xb_ = 0, xc_ = 0;                               \
            for (int q_ = 0; q_ < 8; ++q_) {                             \
                size_t ri_ = rem_ ? (size_t)(rbase_ + __builtin_ctz(rem_)) \
                                  : (size_t)ZROWI;                       \
                rem_ &= rem_ - 1u;                                       \
                const u64* rp_ = mask + ri_ * NW;                        \
                ulonglong2 v_ = *(const ulonglong2*)(rp_ + 2 * lane);    \
                xa_ |= v_.x; xb_ |= v_.y; xc_ |= rp_[tw];                \
            }                                                            \
            Ra |= xa_; Rb |= xb_; Rc |= xc_;                             \
        }                                                                \
        step_barrier();                                                  \
    } while (0)

        for (int c = 0; c < NW; c += 2) {
            STEP1(c + 0, P);
            STEP1(c + 1, Q);
        }
#undef STEP1
#undef LROW
#undef CONS
    } else {
        // ---------------- wave 3: L2-warm det_s (268 KB over 132 phases) ------
        const float4* ds = (const float4*)det_s;
        for (int c = 0; c < NW; ++c) {
            int i0 = c * 128 + lane;       i0 = i0 < 16800 ? i0 : 16799;
            int i1 = c * 128 + 64 + lane;  i1 = i1 < 16800 ? i1 : 16799;
            float4 a = ds[i0];
            float4 b = ds[i1];
            asm volatile("" :: "v"(a.x), "v"(b.x));   // keep loads live (rule #17)
            step_barrier();
        }
    }

    // ---- fused write-out: per ROW, vector loads + scalar stores ----
    __syncthreads();
    for (int r = tid; r < N_BOX; r += 256) {
        bool k = (Lbuf[r >> 6] >> (r & 63)) & 1ull;
        const float4* dr = (const float4*)(det_s + (size_t)r * 8);
        float4 b0 = dr[0], b1 = dr[1];
        float* op = out + (size_t)r * 7;
        op[0] = k ? b0.x : 0.0f;
        op[1] = k ? b0.y : 0.0f;
        op[2] = k ? b0.z : 0.0f;
        op[3] = k ? b0.w : 0.0f;
        op[4] = k ? b1.x : 0.0f;
        op[5] = k ? b1.y : 0.0f;
        op[6] = k ? b1.z : 0.0f;
    }
}

extern "C" void kernel_launch(void* const* d_in, const int* in_sizes, int n_in,
                              void* d_out, int out_size, void* d_ws, size_t ws_size,
                              hipStream_t stream) {
    const float* pred = (const float*)d_in[0];
    char* ws = (char*)d_ws;
    float*    det     = (float*)   (ws + OFF_DET);
    u64*      diagT   = (u64*)     (ws + OFF_DIAGT);
    u64*      sup1    = (u64*)     (ws + OFF_SUP1);
    u64*      sup2    = (u64*)     (ws + OFF_SUP2);
    u64*      sup3    = (u64*)     (ws + OFF_SUP3);
    u64*      keys    = (u64*)     (ws + OFF_KEYS);
    float*    det_s   = (float*)   (ws + OFF_DETS);
    float4*   boxes_s = (float4*)  (ws + OFF_BOXESS);
    u64*      mask    = (u64*)     (ws + OFF_MASK);
    int*      vcount  = (int*)     (ws + OFF_VCNT);

    prep_k<<<132, 256, 0, stream>>>(pred, det, keys, mask);
    rank_k<<<264, 256, 0, stream>>>(keys, det, (float4*)det_s, boxes_s, vcount);
    mask_k<<<(NTILE + 3) / 4, 256, 0, stream>>>(boxes_s, mask, diagT, sup1, sup2, sup3);
    scan_k<<<1, 256, 0, stream>>>(mask, diagT, sup1, sup2, sup3, vcount,
                                  det_s, (float*)d_out);
}

// Round 16
// 138.589 us; speedup vs baseline: 1.4626x; 1.0332x over previous
//
#include <hip/hip_runtime.h>
#include <stdint.h>

#define N_BOX 8400
#define NCLS 80
#define PSTRIDE 85
#define NW 132            // 64-box blocks covering 8400
#define NPAIR 66          // 2 blocks per scan phase
#define NTILE 8778        // NW*(NW+1)/2 upper-tri tiles
#define ZROWI N_BOX       // mask row 8400 = all zeros (dummy row target)
#define CONF_T 0.01f
#define NMS_T 0.2f

typedef unsigned long long u64;

// ws layout (bytes). diagT/sup1..3 ALIAS det+keys head (dead after rank_k);
// sup4/sup5 live past vcount (ws >= 9778660, proven by R1's layout passing).
#define OFF_DET     0                    // 8400 x 8 f32   = 268800
#define OFF_DIAGT   0                    // 132*64 u64     = 67584  (alias)
#define OFF_SUP1    67584                // 132*64 u64     = 67584  (alias)
#define OFF_SUP2    135168               // 132*64 u64     = 67584  (alias)
#define OFF_SUP3    202752               // 132*64 u64     = 67584  (alias, tail overlaps keys head — keys dead then)
#define OFF_KEYS    268800               // 8400 u64       = 67200
#define OFF_DETS    336000               // 8400 x 8 f32   = 268800
#define OFF_BOXESS  604800               // 8400 float4    = 134400
#define OFF_MASK    739200               // 8401 x 132 u64 = 8871456 (row 8400 = zeros)
#define OFF_VCNT    9611712              // 1 int
#define OFF_SUP4    9611728              // 132*64 u64     = 67584
#define OFF_SUP5    9679312              // 132*64 u64     = 67584  (ends 9746896 < 9778660)

__device__ __forceinline__ unsigned fmap_desc(float f) {
    unsigned u = __float_as_uint(f);
    unsigned m = (u & 0x80000000u) ? ~u : (u | 0x80000000u); // monotone ascending
    return ~m;                                               // descending
}

__device__ __forceinline__ u64 readlane64(u64 v, int lane) {
    unsigned lo = (unsigned)__builtin_amdgcn_readlane((int)(unsigned)v, lane);
    unsigned hi = (unsigned)__builtin_amdgcn_readlane((int)(unsigned)(v >> 32), lane);
    return ((u64)hi << 32) | lo;
}

__device__ __forceinline__ u64 shfl_xor64(u64 v, int m) {
    int lo = __shfl_xor((int)(unsigned)v, m);
    int hi = __shfl_xor((int)(unsigned)(v >> 32), m);
    return ((u64)(unsigned)hi << 32) | (unsigned)lo;
}

// 64x64 bit-matrix transpose across lanes. Verified R8-R15 (absmax 0).
__device__ __forceinline__ u64 bittranspose64(u64 x, int lane) {
    const u64 P0 = 0x5555555555555555ull, P1 = 0x3333333333333333ull,
              P2 = 0x0F0F0F0F0F0F0F0Full, P3 = 0x00FF00FF00FF00FFull,
              P4 = 0x0000FFFF0000FFFFull, P5 = 0x00000000FFFFFFFFull;
#define TSTEP(s, p) do {                                                 \
        u64 y = shfl_xor64(x, s);                                        \
        x = (lane & (s)) ? ((x & ~(p)) | ((y & ~(p)) >> (s)))            \
                         : ((x & (p))  | ((y & (p))  << (s)));           \
    } while (0)
    TSTEP(1, P0); TSTEP(2, P1); TSTEP(4, P2);
    TSTEP(8, P3); TSTEP(16, P4); TSTEP(32, P5);
#undef TSTEP
    return x;
}

__device__ __forceinline__ u64 wmask(int w, int V) {
    int nb = V - (w << 6);
    if (nb <= 0) return 0ull;
    if (nb >= 64) return ~0ull;
    return (1ull << nb) - 1ull;
}

// Raw barrier: LDS drained, vmcnt pipeline PRESERVED (no __syncthreads drain).
__device__ __forceinline__ void step_barrier() {
    asm volatile("s_waitcnt lgkmcnt(0)" ::: "memory");
    __builtin_amdgcn_s_barrier();
    asm volatile("" ::: "memory");
}

// ---- kernel A: per-row preprocess, 4 lanes per row; zeroes mask row 8400 ----
__global__ __launch_bounds__(256) void prep_k(const float* __restrict__ pred,
                                              float* __restrict__ det,
                                              u64* __restrict__ keys,
                                              u64* __restrict__ mask) {
    if (blockIdx.x == 0 && threadIdx.x < NW)
        mask[(size_t)ZROWI * NW + threadIdx.x] = 0ull;
    int gt = blockIdx.x * 256 + threadIdx.x;
    int i = gt >> 2, q = gt & 3;
    if (i >= N_BOX) return;
    const float* p = pred + (size_t)i * PSTRIDE;
    int cbase = q * 20;
    float best = p[5 + cbase];
    int arg = cbase;
    for (int c = 1; c < 20; ++c) {
        float v = p[5 + cbase + c];
        if (v > best) { best = v; arg = cbase + c; }   // strict > : first max in segment
    }
    // quad-combine: larger value wins; tie -> smaller class index (numpy first-max)
    for (int d = 1; d < 4; d <<= 1) {
        float ob = __shfl_xor(best, d);
        int   oa = __shfl_xor(arg, d);
        if (ob > best || (ob == best && oa < arg)) { best = ob; arg = oa; }
    }
    if (q == 0) {
        float cx = p[0], cy = p[1], w = p[2], h = p[3], obj = p[4];
        float hw = __fmul_rn(w, 0.5f), hh = __fmul_rn(h, 0.5f);
        float x1 = __fsub_rn(cx, hw), y1 = __fsub_rn(cy, hh);
        float x2 = __fadd_rn(cx, hw), y2 = __fadd_rn(cy, hh);
        bool valid = (obj >= CONF_T);
        float score = valid ? obj : -1.0f;
        keys[i] = ((u64)fmap_desc(score) << 32) | (unsigned)i;  // asc => score desc, idx asc
        float4* dr = (float4*)(det + (size_t)i * 8);
        dr[0] = make_float4(x1, y1, x2, y2);
        dr[1] = make_float4(obj, best, (float)arg, 0.0f);
    }
}

// ---- kernel B: rank + scatter. u64 keys (index embedded), 8 j-slices. ----
__global__ __launch_bounds__(256) void rank_k(const u64* __restrict__ keys,
                                              const float* __restrict__ det,
                                              float4* __restrict__ det_s,
                                              float4* __restrict__ boxes_s,
                                              int* __restrict__ vcount) {
    int t = threadIdx.x;
    int i = blockIdx.x * 32 + (t & 31);
    int s = t >> 5;                    // slice 0..7, 1050 keys each
    u64 my = (i < N_BOX) ? keys[i] : ~0ull;
    int cnt = 0, cv = 0;
    int j0 = s * 1050, j1 = j0 + 1050;
    for (int j = j0; j < j1; j += 2) {
        ulonglong2 kk = *(const ulonglong2*)(keys + j);
        cnt += (kk.x < my) + (kk.y < my);
        cv  += ((long long)kk.x >= 0) + ((long long)kk.y >= 0);
    }
    __shared__ int sc[256], sv[256];
    sc[t] = cnt; sv[t] = cv;
    __syncthreads();
    if (t < 32) {
        int r = sc[t] + sc[t + 32] + sc[t + 64] + sc[t + 96]
              + sc[t + 128] + sc[t + 160] + sc[t + 192] + sc[t + 224];
        if (i < N_BOX) {
            const float4* dr = (const float4*)(det + (size_t)i * 8);
            float4 b0 = dr[0], b1 = dr[1];
            det_s[(size_t)r * 2]     = b0;
            det_s[(size_t)r * 2 + 1] = b1;
            boxes_s[r] = b0;
        }
        if (blockIdx.x == 0 && t == 0) {
            *vcount = sv[0] + sv[32] + sv[64] + sv[96]
                    + sv[128] + sv[160] + sv[192] + sv[224];
        }
    }
}

// ---- kernel C: suppression bitmask (upper tri, row-major) + transposed
// near-diagonal tiles diagT/sup1..sup5 (distance 0..5). 4 tiles/block. ----
__global__ __launch_bounds__(256) void mask_k(const float4* __restrict__ boxes_s,
                                              u64* __restrict__ mask,
                                              u64* __restrict__ diagT,
                                              u64* __restrict__ sup1,
                                              u64* __restrict__ sup2,
                                              u64* __restrict__ sup3,
                                              u64* __restrict__ sup4,
                                              u64* __restrict__ sup5) {
    int sub = threadIdx.x >> 6, lane = threadIdx.x & 63;
    int tt = blockIdx.x * 4 + sub;
    bool tv = (tt < NTILE);
    __shared__ float4 cB[4][64];
    __shared__ float  cA[4][64];
    int rb = 0, cb = 0;
    if (tv) {
        rb = (int)((2.0f * NW + 1.0f
                    - sqrtf((2.0f * NW + 1.0f) * (2.0f * NW + 1.0f) - 8.0f * (float)tt)) * 0.5f);
        while (rb > 0 && rb * NW - rb * (rb - 1) / 2 > tt) rb--;
        while ((rb + 1) * NW - (rb + 1) * rb / 2 <= tt) rb++;
        cb = rb + (tt - (rb * NW - rb * (rb - 1) / 2));
        int c0 = cb * 64 + lane;
        float4 b = (c0 < N_BOX) ? boxes_s[c0] : make_float4(0.f, 0.f, 0.f, 0.f);
        cB[sub][lane] = b;
        cA[sub][lane] = __fmul_rn(__fsub_rn(b.z, b.x), __fsub_rn(b.w, b.y));
    }
    __syncthreads();
    if (!tv) return;
    int r = rb * 64 + lane;
    bool inb = (r < N_BOX);
    float4 rx = boxes_s[inb ? r : (N_BOX - 1)];
    float ra = __fmul_rn(__fsub_rn(rx.z, rx.x), __fsub_rn(rx.w, rx.y));
    u64 bits = 0ull;
    int cbase = cb * 64;
    for (int j = 0; j < 64; ++j) {
        int c = cbase + j;
        if (c >= N_BOX || c <= r) continue;    // rows >= N_BOX yield bits==0
        float4 cx4 = cB[sub][j];
        float ltx = fmaxf(rx.x, cx4.x), lty = fmaxf(rx.y, cx4.y);
        float rbx = fminf(rx.z, cx4.z), rby = fminf(rx.w, cx4.w);
        float wx = fmaxf(__fsub_rn(rbx, ltx), 0.0f);
        float wy = fmaxf(__fsub_rn(rby, lty), 0.0f);
        float inter = __fmul_rn(wx, wy);
        float denom = __fadd_rn(__fsub_rn(__fadd_rn(ra, cA[sub][j]), inter), 1e-9f);
        float iou = __fdiv_rn(inter, denom);
        if (iou > NMS_T) bits |= (1ull << j);
    }
    if (inb) mask[(size_t)r * NW + cb] = bits;
    int d = cb - rb;
    if (d <= 5) {
        u64 tb = bittranspose64(bits, lane);
        size_t idx = (size_t)cb * 64 + lane;
        if (d == 0)      diagT[idx] = tb;
        else if (d == 1) sup1[idx]  = tb;
        else if (d == 2) sup2[idx]  = tb;
        else if (d == 3) sup3[idx]  = tb;
        else if (d == 4) sup4[idx]  = tb;
        else             sup5[idx]  = tb;
    }
}

// ---- kernel D: 4-wave scan, 2 BLOCKS PER PHASE (66 phases) ----
// wave 0 (resolver), phase t, blocks e=2t,o=2t+1:
//   cur_e = remvP[e] | bal(s1e&A1..s4e&A4); resolve L_e via diag ballots;
//   cur_o = remvP[o] | bal(s1o&L_e, s2o&A1..s5o&A4); resolve L_o.
//   Shift A4<-A2, A3<-A1, A2<-L_e, A1<-L_o. (remvP[k] covers blocks <=k-5;
//   patches cover k-1..k-4 (even) / k-1..k-5 (odd) — verified k=0..7.)
// waves 1,2 (row-OR, split by leader half-word), phase t:
//   consume other-set slots issued at t-1 (rows of blocks 2t-4, 2t-3);
//   publish remvP[2t+2], [2t+3] (covers <=2t-3 + any extras: still valid);
//   read Lbuf[2t-2], [2t-1]; issue own 2x<=4 slot loads; extras drain 8/batch.
// wave 3: writes out blocks 2t-2, 2t-1 during the scan (Lbuf final at t-1).
// Raw s_barrier per phase preserves each wave's vmcnt pipeline.
__global__ __launch_bounds__(256, 1) void scan_k(const u64* __restrict__ mask,
                                                 const u64* __restrict__ diagT,
                                                 const u64* __restrict__ sup1,
                                                 const u64* __restrict__ sup2,
                                                 const u64* __restrict__ sup3,
                                                 const u64* __restrict__ sup4,
                                                 const u64* __restrict__ sup5,
                                                 const int* __restrict__ vcount,
                                                 const float* __restrict__ det_s,
                                                 float* __restrict__ out) {
    __shared__ u64 remvP1[NW + 4];
    __shared__ u64 remvP2[NW + 4];
    __shared__ u64 Lbuf[NW];
    int tid = threadIdx.x, lane = tid & 63, wv = tid >> 6;
    int V = *vcount;
    for (int i = tid; i < NW + 4; i += 256) { remvP1[i] = 0ull; remvP2[i] = 0ull; }
    for (int i = tid; i < NW; i += 256) Lbuf[i] = 0ull;
    __syncthreads();

    if (wv == 0) {
        // ---------------- wave 0: resolver, 2 blocks/phase ----------------
        u64 A1 = 0ull, A2 = 0ull, A3 = 0ull, A4 = 0ull;
        u64 dEP,s1EP,s2EP,s3EP,s4EP, dOP,s1OP,s2OP,s3OP,s4OP,s5OP;
        u64 dEQ,s1EQ,s2EQ,s3EQ,s4EQ, dOQ,s1OQ,s2OQ,s3OQ,s4OQ,s5OQ;
#define TL(S, pp) do {                                                   \
        int p_ = (pp) < NPAIR ? (pp) : (NPAIR - 1);                      \
        size_t ex_ = (size_t)(2 * p_) * 64 + lane;                       \
        size_t ox_ = ex_ + 64;                                           \
        dE##S = diagT[ex_]; s1E##S = sup1[ex_]; s2E##S = sup2[ex_];      \
        s3E##S = sup3[ex_]; s4E##S = sup4[ex_];                          \
        dO##S = diagT[ox_]; s1O##S = sup1[ox_]; s2O##S = sup2[ox_];      \
        s3O##S = sup3[ox_]; s4O##S = sup4[ox_]; s5O##S = sup5[ox_];      \
    } while (0)
#define RES(curv, dd, mm, Lout) do {                                     \
        u64 ns_ = (~(curv)) & (mm);                                      \
        Lout = 0ull;                                                     \
        while (ns_) {                                                    \
            int b_ = __builtin_ctzll(ns_);                               \
            Lout |= 1ull << b_;                                          \
            u64 sup_ = __ballot((int)((dd >> b_) & 1ull));               \
            ns_ &= ~sup_;                                                \
            ns_ &= ~(1ull << b_);                                        \
        }                                                                \
    } while (0)
#define STEP0(tt_, S) do {                                               \
        int e_ = 2 * (tt_), o_ = e_ + 1;                                 \
        u64 cur_ = remvP1[e_] | remvP2[e_];                              \
        cur_ |= __ballot((s1E##S & A1) != 0ull);                         \
        cur_ |= __ballot((s2E##S & A2) != 0ull);                         \
        cur_ |= __ballot((s3E##S & A3) != 0ull);                         \
        cur_ |= __ballot((s4E##S & A4) != 0ull);                         \
        u64 Le_;                                                         \
        RES(cur_, dE##S, wmask(e_, V), Le_);                             \
        u64 curo_ = remvP1[o_] | remvP2[o_];                             \
        curo_ |= __ballot((s1O##S & Le_) != 0ull);                       \
        curo_ |= __ballot((s2O##S & A1) != 0ull);                        \
        curo_ |= __ballot((s3O##S & A2) != 0ull);                        \
        curo_ |= __ballot((s4O##S & A3) != 0ull);                        \
        curo_ |= __ballot((s5O##S & A4) != 0ull);                        \
        u64 Lo_;                                                         \
        RES(curo_, dO##S, wmask(o_, V), Lo_);                            \
        if (lane == 0) { Lbuf[e_] = Le_; Lbuf[o_] = Lo_; }               \
        A4 = A2; A3 = A1; A2 = Le_; A1 = Lo_;                            \
        TL(S, (tt_) + 2);                                                \
        step_barrier();                                                  \
    } while (0)
        TL(P, 0);
        TL(Q, 1);
        for (int t = 0; t < NPAIR; t += 2) {
            STEP0(t, P);
            STEP0(t + 1, Q);
        }
#undef STEP0
#undef RES
#undef TL
    } else if (wv <= 2) {
        // ------------- waves 1,2: row-OR, split by leader half-word -------------
        int half = wv - 1;                     // 0: leader bits 0..31, 1: 32..63
        u64* myP = half ? remvP2 : remvP1;
        int tw = (lane < 4) ? (128 + lane) : 131;
        u64 Ra = 0ull, Rb = 0ull, Rc = 0ull;   // this wave's partial remv
        u64 Pa0=0,Pa1=0,Pa2=0,Pa3=0,Pa4=0,Pa5=0,Pa6=0,Pa7=0;
        u64 Pb0=0,Pb1=0,Pb2=0,Pb3=0,Pb4=0,Pb5=0,Pb6=0,Pb7=0;
        u64 Pc0=0,Pc1=0,Pc2=0,Pc3=0,Pc4=0,Pc5=0,Pc6=0,Pc7=0;
        u64 Qa0=0,Qa1=0,Qa2=0,Qa3=0,Qa4=0,Qa5=0,Qa6=0,Qa7=0;
        u64 Qb0=0,Qb1=0,Qb2=0,Qb3=0,Qb4=0,Qb5=0,Qb6=0,Qb7=0;
        u64 Qc0=0,Qc1=0,Qc2=0,Qc3=0,Qc4=0,Qc5=0,Qc6=0,Qc7=0;

#define CONS(S) do {                                                     \
        Ra |= ((S##a0|S##a1)|(S##a2|S##a3))|((S##a4|S##a5)|(S##a6|S##a7));\
        Rb |= ((S##b0|S##b1)|(S##b2|S##b3))|((S##b4|S##b5)|(S##b6|S##b7));\
        Rc |= ((S##c0|S##c1)|(S##c2|S##c3))|((S##c4|S##c5)|(S##c6|S##c7));\
    } while (0)

#define PUB(w_) do {                                                     \
        u64 rw_ = ((w_) < 128) ? (((w_) & 1) ? Rb : Ra) : Rc;            \
        int sl_ = ((w_) < 128) ? ((w_) >> 1) : ((w_) - 128);             \
        u64 pv_ = readlane64(rw_, sl_);                                  \
        if (lane == 0) myP[w_] = pv_;                                    \
    } while (0)

#define LROW(S, i, remv_, rbase_) do {                                   \
        size_t ri_ = (remv_) ? (size_t)((rbase_) + __builtin_ctz(remv_)) \
                             : (size_t)ZROWI;                            \
        (remv_) &= (remv_) - 1u;                                         \
        const u64* rp_ = mask + ri_ * NW;                                \
        ulonglong2 v_ = *(const ulonglong2*)(rp_ + 2 * lane);            \
        S##a##i = v_.x; S##b##i = v_.y; S##c##i = rp_[tw];               \
    } while (0)

#define XTRA(remv_, rbase_) do {                                         \
        while (remv_) {                                                  \
            u64 xa_ = 0, xb_ = 0, xc_ = 0;                               \
            for (int q_ = 0; q_ < 8; ++q_) {                             \
                size_t ri_ = (remv_) ? (size_t)((rbase_) + __builtin_ctz(remv_)) \
                                     : (size_t)ZROWI;                    \
                (remv_) &= (remv_) - 1u;                                 \
                const u64* rp_ = mask + ri_ * NW;                        \
                ulonglong2 v_ = *(const ulonglong2*)(rp_ + 2 * lane);    \
                xa_ |= v_.x; xb_ |= v_.y; xc_ |= rp_[tw];                \
            }                                                            \
            Ra |= xa_; Rb |= xb_; Rc |= xc_;                             \
        }                                                                \
    } while (0)

#define STEP1(tt_, Siss, Scon) do {                                      \
        int t_ = (tt_);                                                  \
        CONS(Scon);                     /* rows of blocks 2t-4, 2t-3 */  \
        PUB(2 * t_ + 2);                                                 \
        PUB(2 * t_ + 3);                                                 \
        u64 Le_ = (t_ >= 1) ? Lbuf[2 * t_ - 2] : 0ull;                   \
        u64 Lo_ = (t_ >= 1) ? Lbuf[2 * t_ - 1] : 0ull;                   \
        unsigned re_ = half ? (unsigned)(Le_ >> 32) : (unsigned)Le_;     \
        unsigned ro_ = half ? (unsigned)(Lo_ >> 32) : (unsigned)Lo_;     \
        int rbe_ = ((2 * t_ - 2) << 6) + 32 * half;                      \
        int rbo_ = rbe_ + 64;                                            \
        LROW(Siss, 0, re_, rbe_); LROW(Siss, 1, re_, rbe_);              \
        LROW(Siss, 2, re_, rbe_); LROW(Siss, 3, re_, rbe_);              \
        LROW(Siss, 4, ro_, rbo_); LROW(Siss, 5, ro_, rbo_);              \
        LROW(Siss, 6, ro_, rbo_); LROW(Siss, 7, ro_, rbo_);              \
        XTRA(re_, rbe_);                                                 \
        XTRA(ro_, rbo_);                                                 \
        step_barrier();                                                  \
    } while (0)

        for (int t = 0; t < NPAIR; t += 2) {
            STEP1(t, P, Q);
            STEP1(t + 1, Q, P);
        }
#undef STEP1
#undef XTRA
#undef LROW
#undef PUB
#undef CONS
    } else {
        // ------- wave 3: in-loop write-out of blocks 2t-2, 2t-1 -------
        for (int t = 0; t < NPAIR; ++t) {
            if (t >= 1) {
                int r0 = (2 * t - 2) * 64 + lane;      // always < 8320 < N_BOX
                int r1 = r0 + 64;
                bool k0 = (Lbuf[2 * t - 2] >> lane) & 1ull;
                bool k1 = (Lbuf[2 * t - 1] >> lane) & 1ull;
                const float4* d0 = (const float4*)(det_s + (size_t)r0 * 8);
                const float4* d1 = (const float4*)(det_s + (size_t)r1 * 8);
                float4 a0 = d0[0], a1 = d0[1], b0 = d1[0], b1 = d1[1];
                float* o0 = out + (size_t)r0 * 7;
                float* o1 = out + (size_t)r1 * 7;
                o0[0]=k0?a0.x:0.f; o0[1]=k0?a0.y:0.f; o0[2]=k0?a0.z:0.f;
                o0[3]=k0?a0.w:0.f; o0[4]=k0?a1.x:0.f; o0[5]=k0?a1.y:0.f;
                o0[6]=k0?a1.z:0.f;
                o1[0]=k1?b0.x:0.f; o1[1]=k1?b0.y:0.f; o1[2]=k1?b0.z:0.f;
                o1[3]=k1?b0.w:0.f; o1[4]=k1?b1.x:0.f; o1[5]=k1?b1.y:0.f;
                o1[6]=k1?b1.z:0.f;
            }
            step_barrier();
        }
    }

    // ---- tail: blocks 130,131 (rows 8320..8399) ----
    __syncthreads();
    for (int r = 8320 + tid; r < N_BOX; r += 256) {
        bool k = (Lbuf[r >> 6] >> (r & 63)) & 1ull;
        const float4* dr = (const float4*)(det_s + (size_t)r * 8);
        float4 b0 = dr[0], b1 = dr[1];
        float* op = out + (size_t)r * 7;
        op[0] = k ? b0.x : 0.0f;
        op[1] = k ? b0.y : 0.0f;
        op[2] = k ? b0.z : 0.0f;
        op[3] = k ? b0.w : 0.0f;
        op[4] = k ? b1.x : 0.0f;
        op[5] = k ? b1.y : 0.0f;
        op[6] = k ? b1.z : 0.0f;
    }
}

extern "C" void kernel_launch(void* const* d_in, const int* in_sizes, int n_in,
                              void* d_out, int out_size, void* d_ws, size_t ws_size,
                              hipStream_t stream) {
    const float* pred = (const float*)d_in[0];
    char* ws = (char*)d_ws;
    float*    det     = (float*)   (ws + OFF_DET);
    u64*      diagT   = (u64*)     (ws + OFF_DIAGT);
    u64*      sup1    = (u64*)     (ws + OFF_SUP1);
    u64*      sup2    = (u64*)     (ws + OFF_SUP2);
    u64*      sup3    = (u64*)     (ws + OFF_SUP3);
    u64*      sup4    = (u64*)     (ws + OFF_SUP4);
    u64*      sup5    = (u64*)     (ws + OFF_SUP5);
    u64*      keys    = (u64*)     (ws + OFF_KEYS);
    float*    det_s   = (float*)   (ws + OFF_DETS);
    float4*   boxes_s = (float4*)  (ws + OFF_BOXESS);
    u64*      mask    = (u64*)     (ws + OFF_MASK);
    int*      vcount  = (int*)     (ws + OFF_VCNT);

    prep_k<<<132, 256, 0, stream>>>(pred, det, keys, mask);
    rank_k<<<264, 256, 0, stream>>>(keys, det, (float4*)det_s, boxes_s, vcount);
    mask_k<<<(NTILE + 3) / 4, 256, 0, stream>>>(boxes_s, mask, diagT, sup1, sup2,
                                                sup3, sup4, sup5);
    scan_k<<<1, 256, 0, stream>>>(mask, diagT, sup1, sup2, sup3, sup4, sup5,
                                  vcount, det_s, (float*)d_out);
}